// Round 12
// baseline (149.710 us; speedup 1.0000x reference)
//
#include <hip/hip_runtime.h>
#include <cfloat>

// kNNSelfAttention: softmax(mask*score) with multiplicative -1e19 mask is exactly
// one-hot at argmin_m score[n,m] (validated rounds 1-11).
//   K0: split W into fp16 (hi, lo*2^11) — exact Sterbenz split (1 MB).
//   K1 v3: xp = x@W^T via split-fp16 MFMA, BARRIER-FREE + LDS-FREE: each lane
//       loads its MFMA fragments directly from global (B=wh/wl fp16; A=f32 x,
//       split in-register with the IDENTICAL RNE ops). A prefetched 1 K-step
//       ahead in regs; B issued per-step (L2-hot W panel). Same fragment
//       values + same MFMA order as rounds 8-11 -> xp BITWISE identical ->
//       absmax must stay exactly 0.03125.
//   K2: TRIANGULAR bf16 MFMA score GEMM (tn<=tm, 136 tiles/batch); off-diag
//       tiles emit row-top2 AND col-top2 (symmetry) -> 64 keys/row.
//   K3: top-8 of 64 keys via u32-min butterfly, exact f32 rescore, argmin ->
//       att row + h row.
// Key = (sortable_f32 & 0xFFFFF800) | m_index(11b); min(key) = (min val, min idx).
// Scratch: keys live in each row's own h storage (no cross-block race).
// att region (128MB) scratch: w_hi@32MB, w_lo@33MB, xp16@112MB — all dead
// before finalize writes att. ws (32MB) holds xp.

typedef short bf16x8 __attribute__((ext_vector_type(8)));
typedef _Float16 f16x8 __attribute__((ext_vector_type(8)));
typedef _Float16 f16x4 __attribute__((ext_vector_type(4)));
typedef float f32x4 __attribute__((ext_vector_type(4)));

#define NW4 65536  // 512*512/4

__device__ __forceinline__ unsigned short f2bf(float f) {
  unsigned int u = __float_as_uint(f);
  unsigned int r = (u + 0x7FFFu + ((u >> 16) & 1u)) >> 16;  // RNE
  return (unsigned short)r;
}

__device__ __forceinline__ void gload_lds16(const unsigned short* g, unsigned short* l) {
  __builtin_amdgcn_global_load_lds(
      (const __attribute__((address_space(1))) unsigned int*)g,
      (__attribute__((address_space(3))) unsigned int*)l, 16, 0, 0);
}

// sortable-f32 key: monotone map f32 -> u32, then pack 11-bit index in LSBs.
__device__ __forceinline__ unsigned int skey(float v, int m) {
  unsigned int u = __float_as_uint(v);
  u ^= ((unsigned int)((int)u >> 31)) | 0x80000000u;
  return (u & 0xFFFFF800u) | (unsigned int)m;
}

// K0: exact 2-split of W into fp16 hi + fp16 (lo*2048). One float4/thread.
__global__ __launch_bounds__(256) void splitW_kernel(const float* __restrict__ W,
                                                     _Float16* __restrict__ wh,
                                                     _Float16* __restrict__ wl) {
  const int i4 = blockIdx.x * 256 + threadIdx.x;
  if (i4 >= NW4) return;
  const float4 v = reinterpret_cast<const float4*>(W)[i4];
  f16x4 hv, lv;
  const float vv[4] = {v.x, v.y, v.z, v.w};
#pragma unroll
  for (int c = 0; c < 4; ++c) {
    const _Float16 h = (_Float16)vv[c];
    hv[c] = h;
    lv[c] = (_Float16)((vv[c] - (float)h) * 2048.0f);
  }
  reinterpret_cast<f16x4*>(wh)[i4] = hv;
  reinterpret_cast<f16x4*>(wl)[i4] = lv;
}

// K1 v3: xp[n,o] = sum_k x[n,k]*W[o,k] via split-fp16 MFMA, direct-to-register
// (no LDS, no barriers). 128x128 tile, 4 waves (2x2: 64x64 each), BK=32.
// Per lane: A frag rows = nbase + wr*64 + i*16 + lr, k = t*32 + kg*8 (8 f32);
//           B frag rows = obase + wc*64 + j*16 + lr, same k (8 f16).
// 64B-contiguous per 4-lane kg-group -> L2-friendly; W panel L2/L1-hot.
__global__ __launch_bounds__(256) void gemm_xw_mfma(const float* __restrict__ x,
                                                    const unsigned short* __restrict__ wh,
                                                    const unsigned short* __restrict__ wl,
                                                    float* __restrict__ xp,
                                                    unsigned short* __restrict__ xp16) {
  const int tid = threadIdx.x;
  const int wid = tid >> 6, lane = tid & 63;
  const int lr = lane & 15, kg = lane >> 4;
  const int nbase = blockIdx.x * 128;
  const int obase = blockIdx.y * 128;
  const int wr = wid >> 1, wc = wid & 1;  // wave -> 64x64 quadrant

  const float* gA = x + (size_t)(nbase + wr * 64 + lr) * 512 + kg * 8;
  const unsigned short* gBh = wh + (size_t)(obase + wc * 64 + lr) * 512 + kg * 8;
  const unsigned short* gBl = wl + (size_t)(obase + wc * 64 + lr) * 512 + kg * 8;

  f32x4 acc_hh[4][4] = {};
  f32x4 acc_x[4][4] = {};
  float4 va[4][2];  // A f32 for the CURRENT step (prefetched 1 step ahead)

  // prologue: A for step 0  (row stride between i-frags = 16*512 = 8192 elems)
#pragma unroll
  for (int i = 0; i < 4; ++i) {
    va[i][0] = *reinterpret_cast<const float4*>(gA + i * 8192);
    va[i][1] = *reinterpret_cast<const float4*>(gA + i * 8192 + 4);
  }
  const float* pA = gA + 32;          // A source for step t+1
  const unsigned short* pBh = gBh;    // B source for current step
  const unsigned short* pBl = gBl;

  for (int t = 0; t < 16; ++t) {
    // B fragments for this step (issued early; L2-hot W panel)
    f16x8 bh[4], bl[4];
#pragma unroll
    for (int j = 0; j < 4; ++j) {
      bh[j] = *reinterpret_cast<const f16x8*>(pBh + j * 8192);
      bl[j] = *reinterpret_cast<const f16x8*>(pBl + j * 8192);
    }
    pBh += 32;
    pBl += 32;
#pragma unroll
    for (int i = 0; i < 4; ++i) {
      // split A (identical RNE ops as always -> bitwise-identical fragments)
      f16x8 ah, al;
#pragma unroll
      for (int hf = 0; hf < 2; ++hf) {
        const float vv[4] = {va[i][hf].x, va[i][hf].y, va[i][hf].z, va[i][hf].w};
#pragma unroll
        for (int c = 0; c < 4; ++c) {
          const _Float16 hh = (_Float16)vv[c];
          ah[4 * hf + c] = hh;
          al[4 * hf + c] = (_Float16)((vv[c] - (float)hh) * 2048.0f);
        }
      }
      // prefetch this i-frag's A for step t+1 (full step of latency cover)
      if (t < 15) {
        va[i][0] = *reinterpret_cast<const float4*>(pA + i * 8192);
        va[i][1] = *reinterpret_cast<const float4*>(pA + i * 8192 + 4);
      }
#pragma unroll
      for (int j = 0; j < 4; ++j) {
        acc_hh[i][j] = __builtin_amdgcn_mfma_f32_16x16x32_f16(ah, bh[j], acc_hh[i][j], 0, 0, 0);
        acc_x[i][j]  = __builtin_amdgcn_mfma_f32_16x16x32_f16(ah, bl[j], acc_x[i][j], 0, 0, 0);
        acc_x[i][j]  = __builtin_amdgcn_mfma_f32_16x16x32_f16(al, bh[j], acc_x[i][j], 0, 0, 0);
      }
    }
    pA += 32;
  }

  // Epilogue: C frag layout col=lane&15, row=(lane>>4)*4+reg.
#pragma unroll
  for (int i = 0; i < 4; ++i) {
#pragma unroll
    for (int j = 0; j < 4; ++j) {
#pragma unroll
      for (int r = 0; r < 4; ++r) {
        const float v = acc_hh[i][j][r] + acc_x[i][j][r] * (1.0f / 2048.0f);
        const size_t row = (size_t)(nbase + wr * 64 + i * 16 + kg * 4 + r);
        const int col = obase + wc * 64 + j * 16 + lr;
        xp[row * 512 + col] = v;
        xp16[row * 512 + col] = f2bf(v);
      }
    }
  }
}

// K2: triangular tile enumeration (tn <= tm), 128x128 tile, 4 waves (2x2),
// BK=32, 2-phase dbuf staging. Off-diagonal tiles emit BOTH row-top2 and
// (by symmetry) col-top2 candidates.
__global__ __launch_bounds__(256) void score_kernel(const unsigned short* __restrict__ xp16,
                                                    unsigned int* __restrict__ cand) {
  __shared__ unsigned short lA[2][128 * 32];
  __shared__ unsigned short lB[2][128 * 32];
  const int tid = threadIdx.x;
  const int wid = tid >> 6, lane = tid & 63;
  const int lr = lane & 15, kg = lane >> 4;  // frag row / k-group
  const int b = blockIdx.x & 7;              // batch -> XCD pin
  // unrank triangular pair index p -> (tn, tm), tn <= tm, 136 pairs
  int p = blockIdx.x >> 3;
  int tn = 0, rem = 16;
  while (p >= rem) { p -= rem; rem--; tn++; }
  const int tm = tn + p;
  const int nbase = tn * 128, mbase = tm * 128;
  const unsigned short* Xb = xp16 + (size_t)b * 2048 * 512;
  const int wr = wid >> 1, wc = wid & 1;     // wave -> 64x64 quadrant

  const int srow = tid >> 2;
  const int scol = (tid & 3) * 8;
  const unsigned short* gA0 = Xb + (size_t)(nbase + srow) * 512 + scol;
  const unsigned short* gA1 = Xb + (size_t)(nbase + 64 + srow) * 512 + scol;
  const unsigned short* gB0 = Xb + (size_t)(mbase + srow) * 512 + scol;
  const unsigned short* gB1 = Xb + (size_t)(mbase + 64 + srow) * 512 + scol;

  f32x4 acc[4][4] = {};

#define STAGE(KB, BUF)                                    \
  do {                                                    \
    gload_lds16(gA0 + (KB), &lA[BUF][wid * 512]);         \
    gload_lds16(gA1 + (KB), &lA[BUF][2048 + wid * 512]);  \
    gload_lds16(gB0 + (KB), &lB[BUF][wid * 512]);         \
    gload_lds16(gB1 + (KB), &lB[BUF][2048 + wid * 512]);  \
  } while (0)

#define COMPUTE(BUF)                                                                   \
  do {                                                                                 \
    bf16x8 af[4], bfr[4];                                                              \
    _Pragma("unroll") for (int i2 = 0; i2 < 4; ++i2) {                                 \
      af[i2] = *reinterpret_cast<const bf16x8*>(&lA[BUF][(wr * 64 + i2 * 16 + lr) * 32 + kg * 8]); \
      bfr[i2] = *reinterpret_cast<const bf16x8*>(&lB[BUF][(wc * 64 + i2 * 16 + lr) * 32 + kg * 8]); \
    }                                                                                  \
    _Pragma("unroll") for (int i2 = 0; i2 < 4; ++i2)                                   \
        _Pragma("unroll") for (int j2 = 0; j2 < 4; ++j2)                               \
            acc[i2][j2] =                                                              \
                __builtin_amdgcn_mfma_f32_16x16x32_bf16(af[i2], bfr[j2], acc[i2][j2], 0, 0, 0); \
  } while (0)

  STAGE(0, 0);
  __syncthreads();  // drain prologue stage
  for (int t = 0; t < 15; ++t) {
    STAGE((t + 1) * 32, (t & 1) ^ 1);  // issue next tile first (overlaps MFMA)
    COMPUTE(t & 1);
    __syncthreads();  // drains vmcnt(0): next tile staged; cur reads done
  }
  COMPUTE(1);

  // Row-path epilogue: branchless top-2 per row over this wave's 64 cols.
  const int mcol = mbase + wc * 64 + lr;
#pragma unroll
  for (int i = 0; i < 4; ++i) {
#pragma unroll
    for (int r = 0; r < 4; ++r) {
      const unsigned int x0 = skey(acc[i][0][r], mcol + 0);
      const unsigned int x1 = skey(acc[i][1][r], mcol + 16);
      const unsigned int x2 = skey(acc[i][2][r], mcol + 32);
      const unsigned int x3 = skey(acc[i][3][r], mcol + 48);
      const unsigned int lo01 = min(x0, x1), hi01 = max(x0, x1);
      const unsigned int lo23 = min(x2, x3), hi23 = max(x2, x3);
      unsigned int k1 = min(lo01, lo23);
      unsigned int k2 = min(max(lo01, lo23), min(hi01, hi23));
#pragma unroll
      for (int off = 1; off < 16; off <<= 1) {
        const unsigned int o1 = (unsigned int)__shfl_xor((int)k1, off);
        const unsigned int o2 = (unsigned int)__shfl_xor((int)k2, off);
        const unsigned int nk1 = min(k1, o1);
        const unsigned int nk2 = min(max(k1, o1), min(k2, o2));
        k1 = nk1;
        k2 = nk2;
      }
      if (lr == 0) {
        const int n = nbase + wr * 64 + i * 16 + kg * 4 + r;
        const uint2 kv = {k1, k2};
        *reinterpret_cast<uint2*>(cand + ((size_t)b * 2048 + n) * 512 + (tm * 2 + wc) * 2) = kv;
      }
    }
  }

  // Col-path epilogue (off-diagonal only): col-top2 = row-top2 of the mirror
  // tile by symmetry. Key packs n-index. Butterfly over kg groups (+-16,+-32).
  if (tn != tm) {
    const int nrow0 = nbase + wr * 64 + kg * 4;  // + i*16 + r
#pragma unroll
    for (int j = 0; j < 4; ++j) {
      unsigned int k1 = 0xFFFFFFFFu, k2 = 0xFFFFFFFFu;
#pragma unroll
      for (int i = 0; i < 4; ++i) {
#pragma unroll
        for (int r = 0; r < 4; ++r) {
          const unsigned int xk = skey(acc[i][j][r], nrow0 + i * 16 + r);
          const unsigned int nk1 = min(k1, xk);
          k2 = min(k2, max(k1, xk));
          k1 = nk1;
        }
      }
#pragma unroll
      for (int off = 16; off < 64; off <<= 1) {
        const unsigned int o1 = (unsigned int)__shfl_xor((int)k1, off);
        const unsigned int o2 = (unsigned int)__shfl_xor((int)k2, off);
        const unsigned int nk1 = min(k1, o1);
        const unsigned int nk2 = min(max(k1, o1), min(k2, o2));
        k1 = nk1;
        k2 = nk2;
      }
      if (kg == 0) {
        const int m = mbase + wc * 64 + j * 16 + lr;
        const uint2 kv = {k1, k2};
        *reinterpret_cast<uint2*>(cand + ((size_t)b * 2048 + m) * 512 + (tn * 2 + wr) * 2) = kv;
      }
    }
  }
#undef STAGE
#undef COMPUTE
}

// K3: per row: top-8 of 64 keys (u32-min butterfly) -> exact f32 rescore ->
// argmin -> write full att row (no memset needed) + h row.
__global__ __launch_bounds__(64) void finalize_kernel(const float* __restrict__ xp,
                                                      float* __restrict__ h,
                                                      float* __restrict__ att) {
  const int l = threadIdx.x;
  const int b = blockIdx.x & 7;  // batch -> XCD pin
  const int n = blockIdx.x >> 3;
  const size_t r = (size_t)b * 2048 + n;

  // own-row key scratch (written by K2 into h region); keys unique per row.
  unsigned int key = reinterpret_cast<const unsigned int*>(h + r * 512)[l];
  int wsel[8];
#pragma unroll
  for (int t = 0; t < 8; ++t) {
    unsigned int m = key;
#pragma unroll
    for (int off = 1; off < 64; off <<= 1)
      m = min(m, (unsigned int)__shfl_xor((int)m, off));
    wsel[t] = (int)(m & 0x7FFu);
    if (key == m) key = 0xFFFFFFFFu;  // invalidate winner
  }

  const float* xb = xp + (size_t)b * 2048 * 512;
  const float* xn = xb + (size_t)n * 512;
  const float4 q0 = reinterpret_cast<const float4*>(xn)[2 * l];
  const float4 q1 = reinterpret_cast<const float4*>(xn)[2 * l + 1];

  float bestv = FLT_MAX;
  int besti = 0x7fffffff;
#pragma unroll
  for (int t = 0; t < 8; ++t) {
    const float* xm = xb + (size_t)wsel[t] * 512;
    const float4 p0 = reinterpret_cast<const float4*>(xm)[2 * l];
    const float4 p1 = reinterpret_cast<const float4*>(xm)[2 * l + 1];
    float s = 0.f;
    s = fmaf(q0.x, p0.x, s); s = fmaf(q0.y, p0.y, s);
    s = fmaf(q0.z, p0.z, s); s = fmaf(q0.w, p0.w, s);
    s = fmaf(q1.x, p1.x, s); s = fmaf(q1.y, p1.y, s);
    s = fmaf(q1.z, p1.z, s); s = fmaf(q1.w, p1.w, s);
#pragma unroll
    for (int off = 1; off < 64; off <<= 1) s += __shfl_xor(s, off);
    if (s < bestv || (s == bestv && wsel[t] < besti)) { bestv = s; besti = wsel[t]; }
  }

  // h row = xp[b, besti, :]
  const float* xs = xb + (size_t)besti * 512;
  const float4 w0 = reinterpret_cast<const float4*>(xs)[2 * l];
  const float4 w1 = reinterpret_cast<const float4*>(xs)[2 * l + 1];
  float* hrow = h + r * 512;
  reinterpret_cast<float4*>(hrow)[2 * l] = w0;
  reinterpret_cast<float4*>(hrow)[2 * l + 1] = w1;

  // att row: zeros + one-hot at besti
  float* arow = att + r * 2048;
#pragma unroll
  for (int s = 0; s < 8; ++s) {
    const int cbase = s * 256 + l * 4;
    float4 v;
    v.x = (cbase + 0 == besti) ? 1.0f : 0.0f;
    v.y = (cbase + 1 == besti) ? 1.0f : 0.0f;
    v.z = (cbase + 2 == besti) ? 1.0f : 0.0f;
    v.w = (cbase + 3 == besti) ? 1.0f : 0.0f;
    reinterpret_cast<float4*>(arow)[s * 64 + l] = v;
  }
}

extern "C" void kernel_launch(void* const* d_in, const int* in_sizes, int n_in,
                              void* d_out, int out_size, void* d_ws, size_t ws_size,
                              hipStream_t stream) {
  const float* x = (const float*)d_in[0];  // [8,2048,512] f32
  const float* W = (const float*)d_in[1];  // [512,512] f32
  float* out = (float*)d_out;
  float* h = out;                              // [8,2048,512]
  float* att = out + (size_t)8 * 2048 * 512;   // [8,2048,2048] (128MB region)
  float* xp = (float*)d_ws;                    // 32 MB f32

  // scratch carved from att region (dead before finalize writes att):
  char* attb = (char*)att;
  _Float16* wh = (_Float16*)(attb + (size_t)32 * 1024 * 1024);  // 0.5MB
  _Float16* wl = (_Float16*)(attb + (size_t)33 * 1024 * 1024);  // 0.5MB
  unsigned short* xp16 = (unsigned short*)(attb + (size_t)112 * 1024 * 1024);  // 16MB

  // K0: split W only
  hipLaunchKernelGGL(splitW_kernel, dim3(NW4 / 256), dim3(256), 0, stream, W, wh, wl);

  // K1: direct-to-register split-fp16 MFMA GEMM -> xp, xp16 (128x128 tiles)
  hipLaunchKernelGGL(gemm_xw_mfma, dim3(16384 / 128, 512 / 128), dim3(256), 0, stream,
                     x, (const unsigned short*)wh, (const unsigned short*)wl, xp, xp16);

  // K2: triangular enumeration: 8 batches x 136 tile-pairs
  hipLaunchKernelGGL(score_kernel, dim3(8 * 136), dim3(256), 0, stream, xp16,
                     (unsigned int*)h);

  hipLaunchKernelGGL(finalize_kernel, dim3(16384), dim3(64), 0, stream, xp, h, att);
}

// Round 13
// 144.760 us; speedup vs baseline: 1.0342x; 1.0342x over previous
//
#include <hip/hip_runtime.h>
#include <cfloat>

// kNNSelfAttention: softmax(mask*score) with multiplicative -1e19 mask is exactly
// one-hot at argmin_m score[n,m] (validated rounds 1-12).
//   K0: split W into fp16 (hi, lo*2^11) — exact Sterbenz split (1 MB).
//   K1 v4: xp = x@W^T via split-fp16 MFMA: hh + 2^-11*(h*l + l*h).
//       A (x) kept OUT of LDS: per-lane f32 loads prefetched one K-step ahead,
//       split in-register with the IDENTICAL RNE ops; B (wh/wl) stays on the
//       proven global_load_lds double-buffer. Halves LDS reads (16->8 b128
//       per wave/step) — round-11 K1 was LDS-pipe-bound 3:1.
//       Fragment values + MFMA order bitwise identical to rounds 8-11 ->
//       xp BITWISE identical -> absmax must stay exactly 0.03125.
//       (Round-12's all-direct variant failed: ~280 VGPR -> 1 wave/SIMD,
//       L2 latency serially exposed. Only A goes direct now.)
//   K2: TRIANGULAR bf16 MFMA score GEMM (tn<=tm, 136 tiles/batch); off-diag
//       tiles emit row-top2 AND col-top2 (symmetry) -> 64 keys/row.
//   K3: top-8 of 64 keys via u32-min butterfly, exact f32 rescore, argmin ->
//       att row + h row.
// Key = (sortable_f32 & 0xFFFFF800) | m_index(11b); min(key) = (min val, min idx).
// Scratch: keys live in each row's own h storage (no cross-block race).
// att region (128MB) scratch: w_hi@32MB, w_lo@33MB, xp16@112MB — all dead
// before finalize writes att. ws (32MB) holds xp.

typedef short bf16x8 __attribute__((ext_vector_type(8)));
typedef _Float16 f16x8 __attribute__((ext_vector_type(8)));
typedef _Float16 f16x4 __attribute__((ext_vector_type(4)));
typedef float f32x4 __attribute__((ext_vector_type(4)));

#define NW4 65536  // 512*512/4

__device__ __forceinline__ unsigned short f2bf(float f) {
  unsigned int u = __float_as_uint(f);
  unsigned int r = (u + 0x7FFFu + ((u >> 16) & 1u)) >> 16;  // RNE
  return (unsigned short)r;
}

__device__ __forceinline__ void gload_lds16(const unsigned short* g, unsigned short* l) {
  __builtin_amdgcn_global_load_lds(
      (const __attribute__((address_space(1))) unsigned int*)g,
      (__attribute__((address_space(3))) unsigned int*)l, 16, 0, 0);
}

// sortable-f32 key: monotone map f32 -> u32, then pack 11-bit index in LSBs.
__device__ __forceinline__ unsigned int skey(float v, int m) {
  unsigned int u = __float_as_uint(v);
  u ^= ((unsigned int)((int)u >> 31)) | 0x80000000u;
  return (u & 0xFFFFF800u) | (unsigned int)m;
}

// K0: exact 2-split of W into fp16 hi + fp16 (lo*2048). One float4/thread.
__global__ __launch_bounds__(256) void splitW_kernel(const float* __restrict__ W,
                                                     _Float16* __restrict__ wh,
                                                     _Float16* __restrict__ wl) {
  const int i4 = blockIdx.x * 256 + threadIdx.x;
  if (i4 >= NW4) return;
  const float4 v = reinterpret_cast<const float4*>(W)[i4];
  f16x4 hv, lv;
  const float vv[4] = {v.x, v.y, v.z, v.w};
#pragma unroll
  for (int c = 0; c < 4; ++c) {
    const _Float16 h = (_Float16)vv[c];
    hv[c] = h;
    lv[c] = (_Float16)((vv[c] - (float)h) * 2048.0f);
  }
  reinterpret_cast<f16x4*>(wh)[i4] = hv;
  reinterpret_cast<f16x4*>(wl)[i4] = lv;
}

// K1 v4: xp[n,o] = sum_k x[n,k]*W[o,k] via split-fp16 MFMA.
// 128x128 tile, 4 waves (2x2: 64x64 each), BK=32.
// B: global_load_lds double-buffer (fp16 hi/lo). A: per-lane f32 global loads
// prefetched one K-step ahead, Sterbenz-split in-register at use time.
__global__ __launch_bounds__(256) void gemm_xw_mfma(const float* __restrict__ x,
                                                    const unsigned short* __restrict__ wh,
                                                    const unsigned short* __restrict__ wl,
                                                    float* __restrict__ xp,
                                                    unsigned short* __restrict__ xp16) {
  __shared__ unsigned short lBh[2][128 * 32];
  __shared__ unsigned short lBl[2][128 * 32];
  const int tid = threadIdx.x;
  const int wid = tid >> 6, lane = tid & 63;
  const int lr = lane & 15, kg = lane >> 4;
  const int nbase = blockIdx.x * 128;
  const int obase = blockIdx.y * 128;
  const int wr = wid >> 1, wc = wid & 1;  // wave -> 64x64 quadrant

  // B staging map: thread t -> row t>>2 (+64), fp16 col (t&3)*8; LDS linear.
  const int srow = tid >> 2;
  const int scol = (tid & 3) * 8;
  const unsigned short* gBh0 = wh + (size_t)(obase + srow) * 512 + scol;
  const unsigned short* gBh1 = wh + (size_t)(obase + 64 + srow) * 512 + scol;
  const unsigned short* gBl0 = wl + (size_t)(obase + srow) * 512 + scol;
  const unsigned short* gBl1 = wl + (size_t)(obase + 64 + srow) * 512 + scol;

  // A direct: lane's fragment rows = nbase + wr*64 + i*16 + lr, k = kg*8..+7.
  const float* gA = x + (size_t)(nbase + wr * 64 + lr) * 512 + kg * 8;

  f32x4 acc_hh[4][4] = {};
  f32x4 acc_x[4][4] = {};
  float4 va[4][2];  // A f32 for the CURRENT step (prefetched 1 step ahead)

#define K1_STAGEB(KB, BUF)                                 \
  do {                                                     \
    gload_lds16(gBh0 + (KB), &lBh[BUF][wid * 512]);        \
    gload_lds16(gBh1 + (KB), &lBh[BUF][2048 + wid * 512]); \
    gload_lds16(gBl0 + (KB), &lBl[BUF][wid * 512]);        \
    gload_lds16(gBl1 + (KB), &lBl[BUF][2048 + wid * 512]); \
  } while (0)

#define K1_LOADA(KB)                                                          \
  do {                                                                        \
    _Pragma("unroll") for (int i = 0; i < 4; ++i) {                           \
      va[i][0] = *reinterpret_cast<const float4*>(gA + (KB) + i * 8192);      \
      va[i][1] = *reinterpret_cast<const float4*>(gA + (KB) + i * 8192 + 4);  \
    }                                                                         \
  } while (0)

  // prologue
  K1_LOADA(0);
  K1_STAGEB(0, 0);
  __syncthreads();

  for (int t = 0; t < 16; ++t) {
    const int buf = t & 1;
    if (t < 15) K1_STAGEB((t + 1) * 32, buf ^ 1);  // B for t+1 (overlaps MFMA)

    // B fragments for this step from LDS
    f16x8 bh[4], bl[4];
#pragma unroll
    for (int j = 0; j < 4; ++j) {
      bh[j] = *reinterpret_cast<const f16x8*>(&lBh[buf][(wc * 64 + j * 16 + lr) * 32 + kg * 8]);
      bl[j] = *reinterpret_cast<const f16x8*>(&lBl[buf][(wc * 64 + j * 16 + lr) * 32 + kg * 8]);
    }
    // split A in-register (identical RNE ops -> bitwise-identical fragments)
    f16x8 ah[4], al[4];
#pragma unroll
    for (int i = 0; i < 4; ++i) {
#pragma unroll
      for (int hf = 0; hf < 2; ++hf) {
        const float vv[4] = {va[i][hf].x, va[i][hf].y, va[i][hf].z, va[i][hf].w};
#pragma unroll
        for (int c = 0; c < 4; ++c) {
          const _Float16 hh = (_Float16)vv[c];
          ah[i][4 * hf + c] = hh;
          al[i][4 * hf + c] = (_Float16)((vv[c] - (float)hh) * 2048.0f);
        }
      }
    }
    if (t < 15) K1_LOADA((t + 1) * 32);  // prefetch A for t+1 (hidden by MFMA+barrier)

#pragma unroll
    for (int i = 0; i < 4; ++i)
#pragma unroll
      for (int j = 0; j < 4; ++j) {
        acc_hh[i][j] = __builtin_amdgcn_mfma_f32_16x16x32_f16(ah[i], bh[j], acc_hh[i][j], 0, 0, 0);
        acc_x[i][j]  = __builtin_amdgcn_mfma_f32_16x16x32_f16(ah[i], bl[j], acc_x[i][j], 0, 0, 0);
        acc_x[i][j]  = __builtin_amdgcn_mfma_f32_16x16x32_f16(al[i], bh[j], acc_x[i][j], 0, 0, 0);
      }
    __syncthreads();  // stage for t+1 complete; all reads of buf done
  }

  // Epilogue: C frag layout col=lane&15, row=(lane>>4)*4+reg.
#pragma unroll
  for (int i = 0; i < 4; ++i) {
#pragma unroll
    for (int j = 0; j < 4; ++j) {
#pragma unroll
      for (int r = 0; r < 4; ++r) {
        const float v = acc_hh[i][j][r] + acc_x[i][j][r] * (1.0f / 2048.0f);
        const size_t row = (size_t)(nbase + wr * 64 + i * 16 + kg * 4 + r);
        const int col = obase + wc * 64 + j * 16 + lr;
        xp[row * 512 + col] = v;
        xp16[row * 512 + col] = f2bf(v);
      }
    }
  }
#undef K1_STAGEB
#undef K1_LOADA
}

// K2: triangular tile enumeration (tn <= tm), 128x128 tile, 4 waves (2x2),
// BK=32, 2-phase dbuf staging. Off-diagonal tiles emit BOTH row-top2 and
// (by symmetry) col-top2 candidates.
__global__ __launch_bounds__(256) void score_kernel(const unsigned short* __restrict__ xp16,
                                                    unsigned int* __restrict__ cand) {
  __shared__ unsigned short lA[2][128 * 32];
  __shared__ unsigned short lB[2][128 * 32];
  const int tid = threadIdx.x;
  const int wid = tid >> 6, lane = tid & 63;
  const int lr = lane & 15, kg = lane >> 4;  // frag row / k-group
  const int b = blockIdx.x & 7;              // batch -> XCD pin
  // unrank triangular pair index p -> (tn, tm), tn <= tm, 136 pairs
  int p = blockIdx.x >> 3;
  int tn = 0, rem = 16;
  while (p >= rem) { p -= rem; rem--; tn++; }
  const int tm = tn + p;
  const int nbase = tn * 128, mbase = tm * 128;
  const unsigned short* Xb = xp16 + (size_t)b * 2048 * 512;
  const int wr = wid >> 1, wc = wid & 1;     // wave -> 64x64 quadrant

  const int srow = tid >> 2;
  const int scol = (tid & 3) * 8;
  const unsigned short* gA0 = Xb + (size_t)(nbase + srow) * 512 + scol;
  const unsigned short* gA1 = Xb + (size_t)(nbase + 64 + srow) * 512 + scol;
  const unsigned short* gB0 = Xb + (size_t)(mbase + srow) * 512 + scol;
  const unsigned short* gB1 = Xb + (size_t)(mbase + 64 + srow) * 512 + scol;

  f32x4 acc[4][4] = {};

#define STAGE(KB, BUF)                                    \
  do {                                                    \
    gload_lds16(gA0 + (KB), &lA[BUF][wid * 512]);         \
    gload_lds16(gA1 + (KB), &lA[BUF][2048 + wid * 512]);  \
    gload_lds16(gB0 + (KB), &lB[BUF][wid * 512]);         \
    gload_lds16(gB1 + (KB), &lB[BUF][2048 + wid * 512]);  \
  } while (0)

#define COMPUTE(BUF)                                                                   \
  do {                                                                                 \
    bf16x8 af[4], bfr[4];                                                              \
    _Pragma("unroll") for (int i2 = 0; i2 < 4; ++i2) {                                 \
      af[i2] = *reinterpret_cast<const bf16x8*>(&lA[BUF][(wr * 64 + i2 * 16 + lr) * 32 + kg * 8]); \
      bfr[i2] = *reinterpret_cast<const bf16x8*>(&lB[BUF][(wc * 64 + i2 * 16 + lr) * 32 + kg * 8]); \
    }                                                                                  \
    _Pragma("unroll") for (int i2 = 0; i2 < 4; ++i2)                                   \
        _Pragma("unroll") for (int j2 = 0; j2 < 4; ++j2)                               \
            acc[i2][j2] =                                                              \
                __builtin_amdgcn_mfma_f32_16x16x32_bf16(af[i2], bfr[j2], acc[i2][j2], 0, 0, 0); \
  } while (0)

  STAGE(0, 0);
  __syncthreads();  // drain prologue stage
  for (int t = 0; t < 15; ++t) {
    STAGE((t + 1) * 32, (t & 1) ^ 1);  // issue next tile first (overlaps MFMA)
    COMPUTE(t & 1);
    __syncthreads();  // drains vmcnt(0): next tile staged; cur reads done
  }
  COMPUTE(1);

  // Row-path epilogue: branchless top-2 per row over this wave's 64 cols.
  const int mcol = mbase + wc * 64 + lr;
#pragma unroll
  for (int i = 0; i < 4; ++i) {
#pragma unroll
    for (int r = 0; r < 4; ++r) {
      const unsigned int x0 = skey(acc[i][0][r], mcol + 0);
      const unsigned int x1 = skey(acc[i][1][r], mcol + 16);
      const unsigned int x2 = skey(acc[i][2][r], mcol + 32);
      const unsigned int x3 = skey(acc[i][3][r], mcol + 48);
      const unsigned int lo01 = min(x0, x1), hi01 = max(x0, x1);
      const unsigned int lo23 = min(x2, x3), hi23 = max(x2, x3);
      unsigned int k1 = min(lo01, lo23);
      unsigned int k2 = min(max(lo01, lo23), min(hi01, hi23));
#pragma unroll
      for (int off = 1; off < 16; off <<= 1) {
        const unsigned int o1 = (unsigned int)__shfl_xor((int)k1, off);
        const unsigned int o2 = (unsigned int)__shfl_xor((int)k2, off);
        const unsigned int nk1 = min(k1, o1);
        const unsigned int nk2 = min(max(k1, o1), min(k2, o2));
        k1 = nk1;
        k2 = nk2;
      }
      if (lr == 0) {
        const int n = nbase + wr * 64 + i * 16 + kg * 4 + r;
        const uint2 kv = {k1, k2};
        *reinterpret_cast<uint2*>(cand + ((size_t)b * 2048 + n) * 512 + (tm * 2 + wc) * 2) = kv;
      }
    }
  }

  // Col-path epilogue (off-diagonal only): col-top2 = row-top2 of the mirror
  // tile by symmetry. Key packs n-index. Butterfly over kg groups (+-16,+-32).
  if (tn != tm) {
    const int nrow0 = nbase + wr * 64 + kg * 4;  // + i*16 + r
#pragma unroll
    for (int j = 0; j < 4; ++j) {
      unsigned int k1 = 0xFFFFFFFFu, k2 = 0xFFFFFFFFu;
#pragma unroll
      for (int i = 0; i < 4; ++i) {
#pragma unroll
        for (int r = 0; r < 4; ++r) {
          const unsigned int xk = skey(acc[i][j][r], nrow0 + i * 16 + r);
          const unsigned int nk1 = min(k1, xk);
          k2 = min(k2, max(k1, xk));
          k1 = nk1;
        }
      }
#pragma unroll
      for (int off = 16; off < 64; off <<= 1) {
        const unsigned int o1 = (unsigned int)__shfl_xor((int)k1, off);
        const unsigned int o2 = (unsigned int)__shfl_xor((int)k2, off);
        const unsigned int nk1 = min(k1, o1);
        const unsigned int nk2 = min(max(k1, o1), min(k2, o2));
        k1 = nk1;
        k2 = nk2;
      }
      if (kg == 0) {
        const int m = mbase + wc * 64 + j * 16 + lr;
        const uint2 kv = {k1, k2};
        *reinterpret_cast<uint2*>(cand + ((size_t)b * 2048 + m) * 512 + (tn * 2 + wr) * 2) = kv;
      }
    }
  }
#undef STAGE
#undef COMPUTE
}

// K3: per row: top-8 of 64 keys (u32-min butterfly) -> exact f32 rescore ->
// argmin -> write full att row (no memset needed) + h row.
__global__ __launch_bounds__(64) void finalize_kernel(const float* __restrict__ xp,
                                                      float* __restrict__ h,
                                                      float* __restrict__ att) {
  const int l = threadIdx.x;
  const int b = blockIdx.x & 7;  // batch -> XCD pin
  const int n = blockIdx.x >> 3;
  const size_t r = (size_t)b * 2048 + n;

  // own-row key scratch (written by K2 into h region); keys unique per row.
  unsigned int key = reinterpret_cast<const unsigned int*>(h + r * 512)[l];
  int wsel[8];
#pragma unroll
  for (int t = 0; t < 8; ++t) {
    unsigned int m = key;
#pragma unroll
    for (int off = 1; off < 64; off <<= 1)
      m = min(m, (unsigned int)__shfl_xor((int)m, off));
    wsel[t] = (int)(m & 0x7FFu);
    if (key == m) key = 0xFFFFFFFFu;  // invalidate winner
  }

  const float* xb = xp + (size_t)b * 2048 * 512;
  const float* xn = xb + (size_t)n * 512;
  const float4 q0 = reinterpret_cast<const float4*>(xn)[2 * l];
  const float4 q1 = reinterpret_cast<const float4*>(xn)[2 * l + 1];

  float bestv = FLT_MAX;
  int besti = 0x7fffffff;
#pragma unroll
  for (int t = 0; t < 8; ++t) {
    const float* xm = xb + (size_t)wsel[t] * 512;
    const float4 p0 = reinterpret_cast<const float4*>(xm)[2 * l];
    const float4 p1 = reinterpret_cast<const float4*>(xm)[2 * l + 1];
    float s = 0.f;
    s = fmaf(q0.x, p0.x, s); s = fmaf(q0.y, p0.y, s);
    s = fmaf(q0.z, p0.z, s); s = fmaf(q0.w, p0.w, s);
    s = fmaf(q1.x, p1.x, s); s = fmaf(q1.y, p1.y, s);
    s = fmaf(q1.z, p1.z, s); s = fmaf(q1.w, p1.w, s);
#pragma unroll
    for (int off = 1; off < 64; off <<= 1) s += __shfl_xor(s, off);
    if (s < bestv || (s == bestv && wsel[t] < besti)) { bestv = s; besti = wsel[t]; }
  }

  // h row = xp[b, besti, :]
  const float* xs = xb + (size_t)besti * 512;
  const float4 w0 = reinterpret_cast<const float4*>(xs)[2 * l];
  const float4 w1 = reinterpret_cast<const float4*>(xs)[2 * l + 1];
  float* hrow = h + r * 512;
  reinterpret_cast<float4*>(hrow)[2 * l] = w0;
  reinterpret_cast<float4*>(hrow)[2 * l + 1] = w1;

  // att row: zeros + one-hot at besti
  float* arow = att + r * 2048;
#pragma unroll
  for (int s = 0; s < 8; ++s) {
    const int cbase = s * 256 + l * 4;
    float4 v;
    v.x = (cbase + 0 == besti) ? 1.0f : 0.0f;
    v.y = (cbase + 1 == besti) ? 1.0f : 0.0f;
    v.z = (cbase + 2 == besti) ? 1.0f : 0.0f;
    v.w = (cbase + 3 == besti) ? 1.0f : 0.0f;
    reinterpret_cast<float4*>(arow)[s * 64 + l] = v;
  }
}

extern "C" void kernel_launch(void* const* d_in, const int* in_sizes, int n_in,
                              void* d_out, int out_size, void* d_ws, size_t ws_size,
                              hipStream_t stream) {
  const float* x = (const float*)d_in[0];  // [8,2048,512] f32
  const float* W = (const float*)d_in[1];  // [512,512] f32
  float* out = (float*)d_out;
  float* h = out;                              // [8,2048,512]
  float* att = out + (size_t)8 * 2048 * 512;   // [8,2048,2048] (128MB region)
  float* xp = (float*)d_ws;                    // 32 MB f32

  // scratch carved from att region (dead before finalize writes att):
  char* attb = (char*)att;
  _Float16* wh = (_Float16*)(attb + (size_t)32 * 1024 * 1024);  // 0.5MB
  _Float16* wl = (_Float16*)(attb + (size_t)33 * 1024 * 1024);  // 0.5MB
  unsigned short* xp16 = (unsigned short*)(attb + (size_t)112 * 1024 * 1024);  // 16MB

  // K0: split W only
  hipLaunchKernelGGL(splitW_kernel, dim3(NW4 / 256), dim3(256), 0, stream, W, wh, wl);

  // K1: A-direct split-fp16 MFMA GEMM -> xp, xp16 (128x128 tiles)
  hipLaunchKernelGGL(gemm_xw_mfma, dim3(16384 / 128, 512 / 128), dim3(256), 0, stream,
                     x, (const unsigned short*)wh, (const unsigned short*)wl, xp, xp16);

  // K2: triangular enumeration: 8 batches x 136 tile-pairs
  hipLaunchKernelGGL(score_kernel, dim3(8 * 136), dim3(256), 0, stream, xp16,
                     (unsigned int*)h);

  hipLaunchKernelGGL(finalize_kernel, dim3(16384), dim3(64), 0, stream, xp, h, att);
}

// Round 14
// 117.672 us; speedup vs baseline: 1.2723x; 1.2302x over previous
//
#include <hip/hip_runtime.h>
#include <cfloat>

// kNNSelfAttention: softmax(mask*score) with multiplicative -1e19 mask is exactly
// one-hot at argmin_m score[n,m] (validated rounds 1-13).
// EXACT REVERT to round-11 configuration (best measured: 118.2 us).
//   K0: split W into fp16 (hi, lo*2^11) — exact Sterbenz split (1 MB).
//   K1: xp = x@W^T via split-fp16 MFMA: hh + 2^-11*(h*l + l*h). x-split fused
//       into staging (f32 -> regs -> identical RNE cvt -> ds_write_b128);
//       B via global_load_lds dbuf. 128x128 tile, 4 waves, BK=32.
//       (Rounds 12/13 tried reg-direct A/B variants: both regressed — the
//       in-register split puts ~160 VALU ops on the load->MFMA dependent path
//       and VGPR pressure costs a wave/SIMD. Keep the LDS-staged form.)
//   K2: TRIANGULAR bf16 MFMA score GEMM (tn<=tm, 136 tiles/batch); off-diag
//       tiles emit row-top2 AND col-top2 (symmetry) -> 64 keys/row.
//   K3: top-8 of 64 keys via u32-min butterfly, exact f32 rescore, argmin ->
//       att row + h row.
// Key = (sortable_f32 & 0xFFFFF800) | m_index(11b); min(key) = (min val, min idx).
// Scratch: keys live in each row's own h storage (no cross-block race).
// att region (128MB) scratch: w_hi@32MB, w_lo@33MB, xp16@112MB — all dead
// before finalize writes att. ws (32MB) holds xp.

typedef short bf16x8 __attribute__((ext_vector_type(8)));
typedef _Float16 f16x8 __attribute__((ext_vector_type(8)));
typedef _Float16 f16x4 __attribute__((ext_vector_type(4)));
typedef float f32x4 __attribute__((ext_vector_type(4)));

#define NW4 65536  // 512*512/4

__device__ __forceinline__ unsigned short f2bf(float f) {
  unsigned int u = __float_as_uint(f);
  unsigned int r = (u + 0x7FFFu + ((u >> 16) & 1u)) >> 16;  // RNE
  return (unsigned short)r;
}

__device__ __forceinline__ void gload_lds16(const unsigned short* g, unsigned short* l) {
  __builtin_amdgcn_global_load_lds(
      (const __attribute__((address_space(1))) unsigned int*)g,
      (__attribute__((address_space(3))) unsigned int*)l, 16, 0, 0);
}

// sortable-f32 key: monotone map f32 -> u32, then pack 11-bit index in LSBs.
__device__ __forceinline__ unsigned int skey(float v, int m) {
  unsigned int u = __float_as_uint(v);
  u ^= ((unsigned int)((int)u >> 31)) | 0x80000000u;
  return (u & 0xFFFFF800u) | (unsigned int)m;
}

// K0: exact 2-split of W into fp16 hi + fp16 (lo*2048). One float4/thread.
__global__ __launch_bounds__(256) void splitW_kernel(const float* __restrict__ W,
                                                     _Float16* __restrict__ wh,
                                                     _Float16* __restrict__ wl) {
  const int i4 = blockIdx.x * 256 + threadIdx.x;
  if (i4 >= NW4) return;
  const float4 v = reinterpret_cast<const float4*>(W)[i4];
  f16x4 hv, lv;
  const float vv[4] = {v.x, v.y, v.z, v.w};
#pragma unroll
  for (int c = 0; c < 4; ++c) {
    const _Float16 h = (_Float16)vv[c];
    hv[c] = h;
    lv[c] = (_Float16)((vv[c] - (float)h) * 2048.0f);
  }
  reinterpret_cast<f16x4*>(wh)[i4] = hv;
  reinterpret_cast<f16x4*>(wl)[i4] = lv;
}

// K1: xp[n,o] = sum_k x[n,k]*W[o,k] via split-fp16 MFMA, fused x-split.
// 128x128 tile, 4 waves (2x2: 64x64 each), BK=32, 2-phase dbuf staging.
__global__ __launch_bounds__(256, 2) void gemm_xw_mfma(const float* __restrict__ x,
                                                       const unsigned short* __restrict__ wh,
                                                       const unsigned short* __restrict__ wl,
                                                       float* __restrict__ xp,
                                                       unsigned short* __restrict__ xp16) {
  __shared__ unsigned short lAh[2][128 * 32];
  __shared__ unsigned short lAl[2][128 * 32];
  __shared__ unsigned short lBh[2][128 * 32];
  __shared__ unsigned short lBl[2][128 * 32];
  const int tid = threadIdx.x;
  const int wid = tid >> 6, lane = tid & 63;
  const int lr = lane & 15, kg = lane >> 4;
  const int nbase = blockIdx.x * 128;
  const int obase = blockIdx.y * 128;
  const int wr = wid >> 1, wc = wid & 1;  // wave -> 64x64 quadrant

  // staging map: thread t -> rows {t>>2, t>>2+64}, fp16/f32 col (t&3)*8 .. +7.
  const int srow = tid >> 2;
  const int scol = (tid & 3) * 8;
  const float* gX0 = x + (size_t)(nbase + srow) * 512 + scol;
  const float* gX1 = x + (size_t)(nbase + 64 + srow) * 512 + scol;
  const unsigned short* gBh0 = wh + (size_t)(obase + srow) * 512 + scol;
  const unsigned short* gBh1 = wh + (size_t)(obase + 64 + srow) * 512 + scol;
  const unsigned short* gBl0 = wl + (size_t)(obase + srow) * 512 + scol;
  const unsigned short* gBl1 = wl + (size_t)(obase + 64 + srow) * 512 + scol;

  f32x4 acc_hh[4][4] = {};
  f32x4 acc_x[4][4] = {};
  float4 va[4];  // rows {srow, srow+64} x 2 float4 each (in-flight x tile)

#define K1_LOADA(KB)                                                \
  do {                                                              \
    va[0] = *reinterpret_cast<const float4*>(gX0 + (KB));           \
    va[1] = *reinterpret_cast<const float4*>(gX0 + (KB) + 4);       \
    va[2] = *reinterpret_cast<const float4*>(gX1 + (KB));           \
    va[3] = *reinterpret_cast<const float4*>(gX1 + (KB) + 4);       \
  } while (0)

// convert 16 f32 -> fp16 hi/lo (identical ops to the old split kernel) and
// write two 16B rows into hi/lo LDS (linear layout, even bank spread).
#define K1_WRITEA(BUF)                                              \
  do {                                                              \
    _Pragma("unroll") for (int p = 0; p < 2; ++p) {                 \
      f16x8 hv, lv;                                                 \
      _Pragma("unroll") for (int q = 0; q < 2; ++q) {               \
        const float vv[4] = {va[2 * p + q].x, va[2 * p + q].y,      \
                             va[2 * p + q].z, va[2 * p + q].w};     \
        _Pragma("unroll") for (int c = 0; c < 4; ++c) {             \
          const _Float16 hh = (_Float16)vv[c];                      \
          hv[4 * q + c] = hh;                                       \
          lv[4 * q + c] = (_Float16)((vv[c] - (float)hh) * 2048.0f);\
        }                                                           \
      }                                                             \
      const int ra = (srow + 64 * p) * 32 + scol;                   \
      *reinterpret_cast<f16x8*>(&lAh[BUF][ra]) = hv;                \
      *reinterpret_cast<f16x8*>(&lAl[BUF][ra]) = lv;                \
    }                                                               \
  } while (0)

#define K1_STAGEB(KB, BUF)                                 \
  do {                                                     \
    gload_lds16(gBh0 + (KB), &lBh[BUF][wid * 512]);        \
    gload_lds16(gBh1 + (KB), &lBh[BUF][2048 + wid * 512]); \
    gload_lds16(gBl0 + (KB), &lBl[BUF][wid * 512]);        \
    gload_lds16(gBl1 + (KB), &lBl[BUF][2048 + wid * 512]); \
  } while (0)

#define K1_COMPUTE(BUF)                                                                \
  do {                                                                                 \
    f16x8 ah[4], al[4], bh[4], bl[4];                                                  \
    _Pragma("unroll") for (int i2 = 0; i2 < 4; ++i2) {                                 \
      ah[i2] = *reinterpret_cast<const f16x8*>(&lAh[BUF][(wr * 64 + i2 * 16 + lr) * 32 + kg * 8]); \
      al[i2] = *reinterpret_cast<const f16x8*>(&lAl[BUF][(wr * 64 + i2 * 16 + lr) * 32 + kg * 8]); \
      bh[i2] = *reinterpret_cast<const f16x8*>(&lBh[BUF][(wc * 64 + i2 * 16 + lr) * 32 + kg * 8]); \
      bl[i2] = *reinterpret_cast<const f16x8*>(&lBl[BUF][(wc * 64 + i2 * 16 + lr) * 32 + kg * 8]); \
    }                                                                                  \
    _Pragma("unroll") for (int i2 = 0; i2 < 4; ++i2)                                   \
        _Pragma("unroll") for (int j2 = 0; j2 < 4; ++j2) {                             \
      acc_hh[i2][j2] = __builtin_amdgcn_mfma_f32_16x16x32_f16(ah[i2], bh[j2], acc_hh[i2][j2], 0, 0, 0); \
      acc_x[i2][j2] = __builtin_amdgcn_mfma_f32_16x16x32_f16(ah[i2], bl[j2], acc_x[i2][j2], 0, 0, 0);   \
      acc_x[i2][j2] = __builtin_amdgcn_mfma_f32_16x16x32_f16(al[i2], bh[j2], acc_x[i2][j2], 0, 0, 0);   \
    }                                                                                  \
  } while (0)

  // prologue: fill buffer 0
  K1_LOADA(0);
  K1_STAGEB(0, 0);
  K1_WRITEA(0);
  __syncthreads();
  for (int t = 0; t < 15; ++t) {
    K1_LOADA((t + 1) * 32);             // issue next x loads (hide under MFMA)
    K1_STAGEB((t + 1) * 32, (t & 1) ^ 1);
    K1_COMPUTE(t & 1);
    K1_WRITEA((t & 1) ^ 1);             // vmcnt wait lands here, post-compute
    __syncthreads();
  }
  K1_COMPUTE(1);

  // Epilogue: C frag layout col=lane&15, row=(lane>>4)*4+reg.
#pragma unroll
  for (int i = 0; i < 4; ++i) {
#pragma unroll
    for (int j = 0; j < 4; ++j) {
#pragma unroll
      for (int r = 0; r < 4; ++r) {
        const float v = acc_hh[i][j][r] + acc_x[i][j][r] * (1.0f / 2048.0f);
        const size_t row = (size_t)(nbase + wr * 64 + i * 16 + kg * 4 + r);
        const int col = obase + wc * 64 + j * 16 + lr;
        xp[row * 512 + col] = v;
        xp16[row * 512 + col] = f2bf(v);
      }
    }
  }
#undef K1_LOADA
#undef K1_WRITEA
#undef K1_STAGEB
#undef K1_COMPUTE
}

// K2: triangular tile enumeration (tn <= tm), 128x128 tile, 4 waves (2x2),
// BK=32, 2-phase dbuf staging. Off-diagonal tiles emit BOTH row-top2 and
// (by symmetry) col-top2 candidates.
__global__ __launch_bounds__(256) void score_kernel(const unsigned short* __restrict__ xp16,
                                                    unsigned int* __restrict__ cand) {
  __shared__ unsigned short lA[2][128 * 32];
  __shared__ unsigned short lB[2][128 * 32];
  const int tid = threadIdx.x;
  const int wid = tid >> 6, lane = tid & 63;
  const int lr = lane & 15, kg = lane >> 4;  // frag row / k-group
  const int b = blockIdx.x & 7;              // batch -> XCD pin
  // unrank triangular pair index p -> (tn, tm), tn <= tm, 136 pairs
  int p = blockIdx.x >> 3;
  int tn = 0, rem = 16;
  while (p >= rem) { p -= rem; rem--; tn++; }
  const int tm = tn + p;
  const int nbase = tn * 128, mbase = tm * 128;
  const unsigned short* Xb = xp16 + (size_t)b * 2048 * 512;
  const int wr = wid >> 1, wc = wid & 1;     // wave -> 64x64 quadrant

  const int srow = tid >> 2;
  const int scol = (tid & 3) * 8;
  const unsigned short* gA0 = Xb + (size_t)(nbase + srow) * 512 + scol;
  const unsigned short* gA1 = Xb + (size_t)(nbase + 64 + srow) * 512 + scol;
  const unsigned short* gB0 = Xb + (size_t)(mbase + srow) * 512 + scol;
  const unsigned short* gB1 = Xb + (size_t)(mbase + 64 + srow) * 512 + scol;

  f32x4 acc[4][4] = {};

#define STAGE(KB, BUF)                                    \
  do {                                                    \
    gload_lds16(gA0 + (KB), &lA[BUF][wid * 512]);         \
    gload_lds16(gA1 + (KB), &lA[BUF][2048 + wid * 512]);  \
    gload_lds16(gB0 + (KB), &lB[BUF][wid * 512]);         \
    gload_lds16(gB1 + (KB), &lB[BUF][2048 + wid * 512]);  \
  } while (0)

#define COMPUTE(BUF)                                                                   \
  do {                                                                                 \
    bf16x8 af[4], bfr[4];                                                              \
    _Pragma("unroll") for (int i2 = 0; i2 < 4; ++i2) {                                 \
      af[i2] = *reinterpret_cast<const bf16x8*>(&lA[BUF][(wr * 64 + i2 * 16 + lr) * 32 + kg * 8]); \
      bfr[i2] = *reinterpret_cast<const bf16x8*>(&lB[BUF][(wc * 64 + i2 * 16 + lr) * 32 + kg * 8]); \
    }                                                                                  \
    _Pragma("unroll") for (int i2 = 0; i2 < 4; ++i2)                                   \
        _Pragma("unroll") for (int j2 = 0; j2 < 4; ++j2)                               \
            acc[i2][j2] =                                                              \
                __builtin_amdgcn_mfma_f32_16x16x32_bf16(af[i2], bfr[j2], acc[i2][j2], 0, 0, 0); \
  } while (0)

  STAGE(0, 0);
  __syncthreads();  // drain prologue stage
  for (int t = 0; t < 15; ++t) {
    STAGE((t + 1) * 32, (t & 1) ^ 1);  // issue next tile first (overlaps MFMA)
    COMPUTE(t & 1);
    __syncthreads();  // drains vmcnt(0): next tile staged; cur reads done
  }
  COMPUTE(1);

  // Row-path epilogue: branchless top-2 per row over this wave's 64 cols.
  const int mcol = mbase + wc * 64 + lr;
#pragma unroll
  for (int i = 0; i < 4; ++i) {
#pragma unroll
    for (int r = 0; r < 4; ++r) {
      const unsigned int x0 = skey(acc[i][0][r], mcol + 0);
      const unsigned int x1 = skey(acc[i][1][r], mcol + 16);
      const unsigned int x2 = skey(acc[i][2][r], mcol + 32);
      const unsigned int x3 = skey(acc[i][3][r], mcol + 48);
      const unsigned int lo01 = min(x0, x1), hi01 = max(x0, x1);
      const unsigned int lo23 = min(x2, x3), hi23 = max(x2, x3);
      unsigned int k1 = min(lo01, lo23);
      unsigned int k2 = min(max(lo01, lo23), min(hi01, hi23));
#pragma unroll
      for (int off = 1; off < 16; off <<= 1) {
        const unsigned int o1 = (unsigned int)__shfl_xor((int)k1, off);
        const unsigned int o2 = (unsigned int)__shfl_xor((int)k2, off);
        const unsigned int nk1 = min(k1, o1);
        const unsigned int nk2 = min(max(k1, o1), min(k2, o2));
        k1 = nk1;
        k2 = nk2;
      }
      if (lr == 0) {
        const int n = nbase + wr * 64 + i * 16 + kg * 4 + r;
        const uint2 kv = {k1, k2};
        *reinterpret_cast<uint2*>(cand + ((size_t)b * 2048 + n) * 512 + (tm * 2 + wc) * 2) = kv;
      }
    }
  }

  // Col-path epilogue (off-diagonal only): col-top2 = row-top2 of the mirror
  // tile by symmetry. Key packs n-index. Butterfly over kg groups (+-16,+-32).
  if (tn != tm) {
    const int nrow0 = nbase + wr * 64 + kg * 4;  // + i*16 + r
#pragma unroll
    for (int j = 0; j < 4; ++j) {
      unsigned int k1 = 0xFFFFFFFFu, k2 = 0xFFFFFFFFu;
#pragma unroll
      for (int i = 0; i < 4; ++i) {
#pragma unroll
        for (int r = 0; r < 4; ++r) {
          const unsigned int xk = skey(acc[i][j][r], nrow0 + i * 16 + r);
          const unsigned int nk1 = min(k1, xk);
          k2 = min(k2, max(k1, xk));
          k1 = nk1;
        }
      }
#pragma unroll
      for (int off = 16; off < 64; off <<= 1) {
        const unsigned int o1 = (unsigned int)__shfl_xor((int)k1, off);
        const unsigned int o2 = (unsigned int)__shfl_xor((int)k2, off);
        const unsigned int nk1 = min(k1, o1);
        const unsigned int nk2 = min(max(k1, o1), min(k2, o2));
        k1 = nk1;
        k2 = nk2;
      }
      if (kg == 0) {
        const int m = mbase + wc * 64 + j * 16 + lr;
        const uint2 kv = {k1, k2};
        *reinterpret_cast<uint2*>(cand + ((size_t)b * 2048 + m) * 512 + (tn * 2 + wr) * 2) = kv;
      }
    }
  }
#undef STAGE
#undef COMPUTE
}

// K3: per row: top-8 of 64 keys (u32-min butterfly) -> exact f32 rescore ->
// argmin -> write full att row (no memset needed) + h row.
__global__ __launch_bounds__(64) void finalize_kernel(const float* __restrict__ xp,
                                                      float* __restrict__ h,
                                                      float* __restrict__ att) {
  const int l = threadIdx.x;
  const int b = blockIdx.x & 7;  // batch -> XCD pin
  const int n = blockIdx.x >> 3;
  const size_t r = (size_t)b * 2048 + n;

  // own-row key scratch (written by K2 into h region); keys unique per row.
  unsigned int key = reinterpret_cast<const unsigned int*>(h + r * 512)[l];
  int wsel[8];
#pragma unroll
  for (int t = 0; t < 8; ++t) {
    unsigned int m = key;
#pragma unroll
    for (int off = 1; off < 64; off <<= 1)
      m = min(m, (unsigned int)__shfl_xor((int)m, off));
    wsel[t] = (int)(m & 0x7FFu);
    if (key == m) key = 0xFFFFFFFFu;  // invalidate winner
  }

  const float* xb = xp + (size_t)b * 2048 * 512;
  const float* xn = xb + (size_t)n * 512;
  const float4 q0 = reinterpret_cast<const float4*>(xn)[2 * l];
  const float4 q1 = reinterpret_cast<const float4*>(xn)[2 * l + 1];

  float bestv = FLT_MAX;
  int besti = 0x7fffffff;
#pragma unroll
  for (int t = 0; t < 8; ++t) {
    const float* xm = xb + (size_t)wsel[t] * 512;
    const float4 p0 = reinterpret_cast<const float4*>(xm)[2 * l];
    const float4 p1 = reinterpret_cast<const float4*>(xm)[2 * l + 1];
    float s = 0.f;
    s = fmaf(q0.x, p0.x, s); s = fmaf(q0.y, p0.y, s);
    s = fmaf(q0.z, p0.z, s); s = fmaf(q0.w, p0.w, s);
    s = fmaf(q1.x, p1.x, s); s = fmaf(q1.y, p1.y, s);
    s = fmaf(q1.z, p1.z, s); s = fmaf(q1.w, p1.w, s);
#pragma unroll
    for (int off = 1; off < 64; off <<= 1) s += __shfl_xor(s, off);
    if (s < bestv || (s == bestv && wsel[t] < besti)) { bestv = s; besti = wsel[t]; }
  }

  // h row = xp[b, besti, :]
  const float* xs = xb + (size_t)besti * 512;
  const float4 w0 = reinterpret_cast<const float4*>(xs)[2 * l];
  const float4 w1 = reinterpret_cast<const float4*>(xs)[2 * l + 1];
  float* hrow = h + r * 512;
  reinterpret_cast<float4*>(hrow)[2 * l] = w0;
  reinterpret_cast<float4*>(hrow)[2 * l + 1] = w1;

  // att row: zeros + one-hot at besti
  float* arow = att + r * 2048;
#pragma unroll
  for (int s = 0; s < 8; ++s) {
    const int cbase = s * 256 + l * 4;
    float4 v;
    v.x = (cbase + 0 == besti) ? 1.0f : 0.0f;
    v.y = (cbase + 1 == besti) ? 1.0f : 0.0f;
    v.z = (cbase + 2 == besti) ? 1.0f : 0.0f;
    v.w = (cbase + 3 == besti) ? 1.0f : 0.0f;
    reinterpret_cast<float4*>(arow)[s * 64 + l] = v;
  }
}

extern "C" void kernel_launch(void* const* d_in, const int* in_sizes, int n_in,
                              void* d_out, int out_size, void* d_ws, size_t ws_size,
                              hipStream_t stream) {
  const float* x = (const float*)d_in[0];  // [8,2048,512] f32
  const float* W = (const float*)d_in[1];  // [512,512] f32
  float* out = (float*)d_out;
  float* h = out;                              // [8,2048,512]
  float* att = out + (size_t)8 * 2048 * 512;   // [8,2048,2048] (128MB region)
  float* xp = (float*)d_ws;                    // 32 MB f32

  // scratch carved from att region (dead before finalize writes att):
  char* attb = (char*)att;
  _Float16* wh = (_Float16*)(attb + (size_t)32 * 1024 * 1024);  // 0.5MB
  _Float16* wl = (_Float16*)(attb + (size_t)33 * 1024 * 1024);  // 0.5MB
  unsigned short* xp16 = (unsigned short*)(attb + (size_t)112 * 1024 * 1024);  // 16MB

  // K0: split W only
  hipLaunchKernelGGL(splitW_kernel, dim3(NW4 / 256), dim3(256), 0, stream, W, wh, wl);

  // K1: fused x-split + split-fp16 MFMA GEMM -> xp, xp16 (128x128 tiles)
  hipLaunchKernelGGL(gemm_xw_mfma, dim3(16384 / 128, 512 / 128), dim3(256), 0, stream,
                     x, (const unsigned short*)wh, (const unsigned short*)wl, xp, xp16);

  // K2: triangular enumeration: 8 batches x 136 tile-pairs
  hipLaunchKernelGGL(score_kernel, dim3(8 * 136), dim3(256), 0, stream, xp16,
                     (unsigned int*)h);

  hipLaunchKernelGGL(finalize_kernel, dim3(16384), dim3(64), 0, stream, xp, h, att);
}